// Round 4
// baseline (704.898 us; speedup 1.0000x reference)
//
#include <hip/hip_runtime.h>
#include <hip/hip_bf16.h>
#include <math.h>

typedef __attribute__((ext_vector_type(8))) short bf16x8;   // 8 bf16 = 4 VGPRs
typedef __attribute__((ext_vector_type(16))) float f32x16;  // 32x32 mfma acc

#define NUM_PRIORS 11640
#define OUT_CH 25
#define BATCH 32

// ---------------- workspace layout (bytes) ----------------
// bf16 weights in MFMA-frag order: [tap][ck][ks][ntile][lane][8]
#define WT0 0u
#define WT1 1474560u
#define WT2 4423680u
#define WT3 5898240u
#define WT4 6635520u
#define WT5 7372800u
// fp32 conv output CONV[s][b][m=y*F+x][n=0..159]
#define CV0 8110080u
#define CV1 37683200u
#define CV2 45076480u
#define CV3 47124480u
#define CV4 47636480u
#define CV5 47820800u
#define WS_TOTAL 47841280u

// ====== weight prepass: OIHW fp32 -> bf16 frag-order [tap][ck][ks][nt][lane][8]
template <int C>
__global__ __launch_bounds__(256)
void wprep(const float* __restrict__ loc_w, const float* __restrict__ conf_w,
           unsigned short* __restrict__ wt)
{
  constexpr int CK = C / 64;
  const int idx = blockIdx.x * 256 + threadIdx.x;
  if (idx >= 1440 * C) return;
  const int j    = idx & 7;
  const int lane = (idx >> 3) & 63;
  int rest = idx >> 9;
  const int nt  = rest % 5;  rest /= 5;
  const int ks  = rest & 3;  rest >>= 2;
  const int ck  = rest % CK;
  const int tap = rest / CK;
  const int n = nt * 32 + (lane & 31);
  const int c = ck * 64 + ks * 16 + (lane >> 5) * 8 + j;
  float v = 0.f;
  if (n < 24)       v = loc_w [((size_t)n        * C + c) * 9 + tap];
  else if (n < 150) v = conf_w[((size_t)(n - 24) * C + c) * 9 + tap];
  __hip_bfloat16 h = __float2bfloat16(v);
  wt[idx] = *(unsigned short*)&h;
}

// ====== implicit-GEMM conv with LDS patch reuse across the 9 taps ========
// block = 256 thr = 4 waves; m-tile 128 (4 x 32), n = 160 (5 x 32); BK = 64 ch
template <int C, int F, int SPLIT, bool ATOMIC>
__global__ __launch_bounds__(256, 2)
void gemm_conv(const float* __restrict__ x, const unsigned short* __restrict__ wt,
               float* __restrict__ cv)
{
  constexpr int FF = F * F;
  constexpr int MB = (FF + 127) / 128;
  constexpr int CK = C / 64;
  constexpr int PCOLS = F + 2;
  constexpr int PR = ((127 / F + 4) < (F + 2)) ? (127 / F + 4) : (F + 2);
  constexpr int N4 = (PR * PCOLS + 3) / 4;   // pos quads
  constexpr int PP = N4 * 4;                 // pos stride (dwords)

  __shared__ unsigned int lP[32 * PP];       // [kk = c/2][pos] bf16-pair

  const int bid = blockIdx.x;
  const int sp  = bid % SPLIT;
  const int mb  = (bid / SPLIT) % MB;
  const int b   = bid / (SPLIT * MB);
  const int ck0 = sp * CK / SPLIT;
  const int ck1 = (sp + 1) * CK / SPLIT;
  const int m0  = mb * 128;
  const int ylo = m0 / F;
  const int mtop = (m0 + 127) < (FF - 1) ? (m0 + 127) : (FF - 1);
  const int yhi = mtop / F;

  const int t    = threadIdx.x;
  const int wave = t >> 6, lane = t & 63;
  const int cm   = lane & 31, khalf = lane >> 5;
  int m_img = m0 + wave * 32 + cm;
  if (m_img > FF - 1) m_img = FF - 1;
  const int ay = m_img / F, ax = m_img - ay * F;
  const int pos0 = (ay - ylo) * PCOLS + ax;  // pa = pos0 + (dy+1)*PCOLS + (dx+1)

  const float* x0 = x + (size_t)b * C * FF;

  f32x16 acc[5];
  #pragma unroll
  for (int nt = 0; nt < 5; ++nt)
    #pragma unroll
    for (int r = 0; r < 16; ++r) acc[nt][r] = 0.f;

  for (int ck = ck0; ck < ck1; ++ck) {
    __syncthreads();
    // ---- stage patch: 64 channels as 32 bf16-pairs, coalesced cols ----
    #pragma unroll 1
    for (int e = t; e < 32 * N4; e += 256) {
      const int kk = e / N4;           // constexpr divisor
      const int u4 = e - kk * N4;
      const float* s0 = x0 + (size_t)(ck * 64 + 2 * kk) * FF;
      const float* s1 = s0 + FF;
      unsigned int pk[4];
      #pragma unroll
      for (int q = 0; q < 4; ++q) {
        const int pos = u4 * 4 + q;
        const int pr  = pos / PCOLS;
        const int pc  = pos - pr * PCOLS;
        const int gy  = ylo - 1 + pr;
        const int gx  = pc - 1;
        float v0 = 0.f, v1 = 0.f;
        if (pos < PR * PCOLS && gy >= 0 && gy < F && gx >= 0 && gx < F) {
          v0 = s0[gy * F + gx];
          v1 = s1[gy * F + gx];
        }
        __hip_bfloat162 h = __float22bfloat162_rn(float2{v0, v1});
        pk[q] = *(unsigned int*)&h;
      }
      uint4 w4; w4.x = pk[0]; w4.y = pk[1]; w4.z = pk[2]; w4.w = pk[3];
      *(uint4*)&lP[kk * PP + u4 * 4] = w4;
    }
    __syncthreads();

    // ---- compute: 9 taps from the same patch; B-frags direct from L2 ----
    const unsigned short* wck = wt + ck * 10240 + lane * 8;
    #pragma unroll
    for (int tap = 0; tap < 9; ++tap) {
      const int dy = tap / 3 - 1, dx = tap % 3 - 1;
      if (ylo + dy >= F || yhi + dy < 0) continue;   // block-uniform skip
      if (F == 1 && dx != 0) continue;
      const int pa = pos0 + (dy + 1) * PCOLS + (dx + 1);
      #pragma unroll
      for (int ks = 0; ks < 4; ++ks) {
        union { bf16x8 v; unsigned int u[4]; } af;
        #pragma unroll
        for (int i = 0; i < 4; ++i)
          af.u[i] = lP[(ks * 8 + khalf * 4 + i) * PP + pa];
        #pragma unroll
        for (int nt = 0; nt < 5; ++nt) {
          bf16x8 bfr = *(const bf16x8*)(wck + tap * (CK * 10240) + ks * 2560 + nt * 512);
          acc[nt] = __builtin_amdgcn_mfma_f32_32x32x16_bf16(af.v, bfr, acc[nt], 0, 0, 0);
        }
      }
    }
  }

  // ---- store / atomic-accumulate ----
  float* cbase = cv + (size_t)b * FF * 160;
  #pragma unroll
  for (int nt = 0; nt < 5; ++nt) {
    const int n = nt * 32 + cm;
    #pragma unroll
    for (int r = 0; r < 16; ++r) {
      const int mm  = wave * 32 + (r & 3) + 8 * (r >> 2) + 4 * khalf;
      const int m_g = m0 + mm;
      if (m_g < FF) {
        if (ATOMIC) atomicAdd(&cbase[(size_t)m_g * 160 + n], acc[nt][r]);
        else        cbase[(size_t)m_g * 160 + n] = acc[nt][r];
      }
    }
  }
}

// ================= decode: bias + softmax + prior decode ==================
struct DecArgs {
  const float* lb[6];
  const float* cb[6];
};

template <int F>
__device__ __forceinline__
void dec_one(int local, int b, const float* cvs, const float* lb, const float* cb,
             const float* p4, float* o)
{
  constexpr int FF = F * F;
  const int pos = local / 6;
  const int a   = local - pos * 6;
  const float* strip = cvs + ((size_t)b * FF + pos) * 160;

  float cls[21];
  float mx = -1e30f;
  #pragma unroll
  for (int k = 0; k < 21; ++k) {
    cls[k] = strip[24 + a * 21 + k] + cb[a * 21 + k];
    mx = fmaxf(mx, cls[k]);
  }
  float s = 0.f;
  #pragma unroll
  for (int k = 0; k < 21; ++k) { cls[k] = __expf(cls[k] - mx); s += cls[k]; }
  const float inv = 1.f / s;

  const float l0 = strip[a * 4 + 0] + lb[a * 4 + 0];
  const float l1 = strip[a * 4 + 1] + lb[a * 4 + 1];
  const float l2 = strip[a * 4 + 2] + lb[a * 4 + 2];
  const float l3 = strip[a * 4 + 3] + lb[a * 4 + 3];

  const float px = p4[0], py = p4[1], pw = p4[2], ph = p4[3];
  const float cx = px + l0 * 0.1f * pw;
  const float cy = py + l1 * 0.1f * ph;
  const float w  = pw * __expf(l2 * 0.2f);
  const float h  = ph * __expf(l3 * 0.2f);
  const float minx = cx - 0.5f * w;
  const float miny = cy - 0.5f * h;

  o[0] = minx; o[1] = miny; o[2] = minx + w; o[3] = miny + h;
  #pragma unroll
  for (int k = 0; k < 21; ++k) o[4 + k] = cls[k] * inv;
}

__global__ __launch_bounds__(256)
void decode_k(const char* __restrict__ wsb, DecArgs da,
              const float* __restrict__ priors, float* __restrict__ out)
{
  const int gid = blockIdx.x * 256 + threadIdx.x;
  if (gid >= BATCH * NUM_PRIORS) return;
  const int b  = gid / NUM_PRIORS;
  const int pr = gid - b * NUM_PRIORS;
  float* o = out + (size_t)gid * OUT_CH;
  const float* p4 = priors + (size_t)pr * 4;

  if (pr < 8664)       dec_one<38>(pr,         b, (const float*)(wsb + CV0), da.lb[0], da.cb[0], p4, o);
  else if (pr < 10830) dec_one<19>(pr - 8664,  b, (const float*)(wsb + CV1), da.lb[1], da.cb[1], p4, o);
  else if (pr < 11430) dec_one<10>(pr - 10830, b, (const float*)(wsb + CV2), da.lb[2], da.cb[2], p4, o);
  else if (pr < 11580) dec_one<5> (pr - 11430, b, (const float*)(wsb + CV3), da.lb[3], da.cb[3], p4, o);
  else if (pr < 11634) dec_one<3> (pr - 11580, b, (const float*)(wsb + CV4), da.lb[4], da.cb[4], p4, o);
  else                 dec_one<1> (pr - 11634, b, (const float*)(wsb + CV5), da.lb[5], da.cb[5], p4, o);
}

// ================= fallback (round-1 direct kernel, known-good) ===========
#define TH 4
#define TW 8
#define NPOS 32
#define NUM_OC 160
#define WS_STRIDE 161
#define OS 33
#define CC 8

union SmemFB {
  struct {
    float patch[CC * (TH + 2) * (TW + 2)];
    float w[9 * CC * WS_STRIDE];
  } st;
  float outbuf[NUM_OC * OS];
};

template <int C, int F>
__global__ __launch_bounds__(256)
void ssd_stage(const float* __restrict__ x,
               const float* __restrict__ loc_w, const float* __restrict__ loc_b,
               const float* __restrict__ conf_w, const float* __restrict__ conf_b,
               const float* __restrict__ priors,
               float* __restrict__ out, int stage_off)
{
  constexpr int nx = (F + TW - 1) / TW;
  constexpr int ny = (F + TH - 1) / TH;
  __shared__ SmemFB smem;

  const int bid = blockIdx.x;
  const int b   = bid / (nx * ny);
  const int rem = bid % (nx * ny);
  const int ty  = rem / nx;
  const int tx  = rem % nx;
  const int x0  = tx * TW;
  const int y0  = ty * TH;

  const int t = threadIdx.x;
  const int g = t & 31;
  const int p = t >> 5;

  float acc[5][TH] = {};

  #pragma unroll 1
  for (int c0 = 0; c0 < C; c0 += CC) {
    __syncthreads();
    for (int i = t; i < CC * (TH + 2) * (TW + 2); i += 256) {
      int c  = i / ((TH + 2) * (TW + 2));
      int r  = i - c * ((TH + 2) * (TW + 2));
      int yy = r / (TW + 2);
      int xx = r - yy * (TW + 2);
      int gy = y0 + yy - 1;
      int gx = x0 + xx - 1;
      float v = 0.f;
      if (gy >= 0 && gy < F && gx >= 0 && gx < F)
        v = x[(((size_t)b * C + (c0 + c)) * F + gy) * F + gx];
      smem.st.patch[i] = v;
    }
    for (int i = t; i < NUM_OC * (CC * 9); i += 256) {
      int oc  = i / (CC * 9);
      int j   = i - oc * (CC * 9);
      int c   = j / 9;
      int tap = j - c * 9;
      float v = 0.f;
      if (oc < 24)        v = loc_w [((size_t)oc        * C + (c0 + c)) * 9 + tap];
      else if (oc < 150)  v = conf_w[((size_t)(oc - 24) * C + (c0 + c)) * 9 + tap];
      smem.st.w[(tap * CC + c) * WS_STRIDE + oc] = v;
    }
    __syncthreads();

    for (int tap = 0; tap < 9; ++tap) {
      const int ky = tap / 3;
      const int kx = tap - ky * 3;
      const int xbase = ky * (TW + 2) + kx + p;
      const int wbase = tap * CC * WS_STRIDE + g;
      #pragma unroll
      for (int c = 0; c < CC; ++c) {
        float xv[TH];
        #pragma unroll
        for (int v = 0; v < TH; ++v)
          xv[v] = smem.st.patch[c * ((TH + 2) * (TW + 2)) + v * (TW + 2) + xbase];
        #pragma unroll
        for (int u = 0; u < 5; ++u) {
          float wv = smem.st.w[wbase + c * WS_STRIDE + u * 32];
          #pragma unroll
          for (int v = 0; v < TH; ++v)
            acc[u][v] += wv * xv[v];
        }
      }
    }
  }

  __syncthreads();
  #pragma unroll
  for (int u = 0; u < 5; ++u) {
    int oc = g + 32 * u;
    float bias = 0.f;
    if (oc < 24)       bias = loc_b[oc];
    else if (oc < 150) bias = conf_b[oc - 24];
    #pragma unroll
    for (int v = 0; v < TH; ++v)
      smem.outbuf[oc * OS + v * TW + p] = acc[u][v] + bias;
  }
  __syncthreads();

  if (t < NPOS * 6) {
    int pos = t / 6;
    int a   = t - pos * 6;
    int lx  = pos & 7;
    int ly  = pos >> 3;
    int gx  = x0 + lx;
    int gy  = y0 + ly;
    if (gx < F && gy < F) {
      float cls[21];
      float m = -1e30f;
      #pragma unroll
      for (int k = 0; k < 21; ++k) {
        cls[k] = smem.outbuf[(24 + a * 21 + k) * OS + pos];
        m = fmaxf(m, cls[k]);
      }
      float s = 0.f;
      #pragma unroll
      for (int k = 0; k < 21; ++k) { cls[k] = __expf(cls[k] - m); s += cls[k]; }
      float inv = 1.f / s;

      float l0 = smem.outbuf[(a * 4 + 0) * OS + pos];
      float l1 = smem.outbuf[(a * 4 + 1) * OS + pos];
      float l2 = smem.outbuf[(a * 4 + 2) * OS + pos];
      float l3 = smem.outbuf[(a * 4 + 3) * OS + pos];

      int prior = stage_off + (gy * F + gx) * 6 + a;
      const float* pr = priors + (size_t)prior * 4;
      float px = pr[0], py = pr[1], pw = pr[2], ph = pr[3];
      float cx = px + l0 * 0.1f * pw;
      float cy = py + l1 * 0.1f * ph;
      float w  = pw * __expf(l2 * 0.2f);
      float h  = ph * __expf(l3 * 0.2f);
      float minx = cx - 0.5f * w;
      float miny = cy - 0.5f * h;

      float* o = out + ((size_t)b * NUM_PRIORS + prior) * OUT_CH;
      o[0] = minx;
      o[1] = miny;
      o[2] = minx + w;
      o[3] = miny + h;
      #pragma unroll
      for (int k = 0; k < 21; ++k)
        o[4 + k] = cls[k] * inv;
    }
  }
}

template <int C, int F>
static void launch_stage_fb(void* const* d_in, int base, const float* priors, float* out,
                            int stage_off, hipStream_t stream) {
  constexpr int nx = (F + TW - 1) / TW;
  constexpr int ny = (F + TH - 1) / TH;
  int blocks = BATCH * nx * ny;
  ssd_stage<C, F><<<blocks, 256, 0, stream>>>(
      (const float*)d_in[base + 0], (const float*)d_in[base + 1], (const float*)d_in[base + 2],
      (const float*)d_in[base + 3], (const float*)d_in[base + 4], priors, out, stage_off);
}

// ================= launch =================================================
extern "C" void kernel_launch(void* const* d_in, const int* in_sizes, int n_in,
                              void* d_out, int out_size, void* d_ws, size_t ws_size,
                              hipStream_t stream) {
  (void)in_sizes; (void)n_in; (void)out_size;
  const float* priors = (const float*)d_in[30];
  float* out = (float*)d_out;

  if (ws_size < (size_t)WS_TOTAL) {   // deterministic fallback
    launch_stage_fb<512,  38>(d_in,  0, priors, out,     0, stream);
    launch_stage_fb<1024, 19>(d_in,  5, priors, out,  8664, stream);
    launch_stage_fb<512,  10>(d_in, 10, priors, out, 10830, stream);
    launch_stage_fb<256,   5>(d_in, 15, priors, out, 11430, stream);
    launch_stage_fb<256,   3>(d_in, 20, priors, out, 11580, stream);
    launch_stage_fb<256,   1>(d_in, 25, priors, out, 11634, stream);
    return;
  }

  char* wsb = (char*)d_ws;

  // weight prepass into MFMA-frag order
  wprep<512> <<<(1440 * 512  + 255) / 256, 256, 0, stream>>>((const float*)d_in[1],  (const float*)d_in[3],  (unsigned short*)(wsb + WT0));
  wprep<1024><<<(1440 * 1024 + 255) / 256, 256, 0, stream>>>((const float*)d_in[6],  (const float*)d_in[8],  (unsigned short*)(wsb + WT1));
  wprep<512> <<<(1440 * 512  + 255) / 256, 256, 0, stream>>>((const float*)d_in[11], (const float*)d_in[13], (unsigned short*)(wsb + WT2));
  wprep<256> <<<(1440 * 256  + 255) / 256, 256, 0, stream>>>((const float*)d_in[16], (const float*)d_in[18], (unsigned short*)(wsb + WT3));
  wprep<256> <<<(1440 * 256  + 255) / 256, 256, 0, stream>>>((const float*)d_in[21], (const float*)d_in[23], (unsigned short*)(wsb + WT4));
  wprep<256> <<<(1440 * 256  + 255) / 256, 256, 0, stream>>>((const float*)d_in[26], (const float*)d_in[28], (unsigned short*)(wsb + WT5));

  // zero the atomic-accumulated conv regions (stages 1..5)
  hipMemsetAsync(wsb + CV1, 0, WS_TOTAL - CV1, stream);

  // implicit-GEMM convs (patch-reuse)
  gemm_conv<512,  38, 1, false><<<32 * 12,    256, 0, stream>>>((const float*)d_in[0],  (const unsigned short*)(wsb + WT0), (float*)(wsb + CV0));
  gemm_conv<1024, 19, 4, true> <<<32 * 3 * 4, 256, 0, stream>>>((const float*)d_in[5],  (const unsigned short*)(wsb + WT1), (float*)(wsb + CV1));
  gemm_conv<512,  10, 8, true> <<<32 * 8,     256, 0, stream>>>((const float*)d_in[10], (const unsigned short*)(wsb + WT2), (float*)(wsb + CV2));
  gemm_conv<256,   5, 4, true> <<<32 * 4,     256, 0, stream>>>((const float*)d_in[15], (const unsigned short*)(wsb + WT3), (float*)(wsb + CV3));
  gemm_conv<256,   3, 4, true> <<<32 * 4,     256, 0, stream>>>((const float*)d_in[20], (const unsigned short*)(wsb + WT4), (float*)(wsb + CV4));
  gemm_conv<256,   1, 4, true> <<<32 * 4,     256, 0, stream>>>((const float*)d_in[25], (const unsigned short*)(wsb + WT5), (float*)(wsb + CV5));

  // epilogue: bias + softmax + decode
  DecArgs da;
  da.lb[0] = (const float*)d_in[2];  da.cb[0] = (const float*)d_in[4];
  da.lb[1] = (const float*)d_in[7];  da.cb[1] = (const float*)d_in[9];
  da.lb[2] = (const float*)d_in[12]; da.cb[2] = (const float*)d_in[14];
  da.lb[3] = (const float*)d_in[17]; da.cb[3] = (const float*)d_in[19];
  da.lb[4] = (const float*)d_in[22]; da.cb[4] = (const float*)d_in[24];
  da.lb[5] = (const float*)d_in[27]; da.cb[5] = (const float*)d_in[29];
  decode_k<<<(BATCH * NUM_PRIORS + 255) / 256, 256, 0, stream>>>((const char*)d_ws, da, priors, out);
}

// Round 5
// 565.680 us; speedup vs baseline: 1.2461x; 1.2461x over previous
//
#include <hip/hip_runtime.h>
#include <hip/hip_bf16.h>
#include <math.h>

typedef __attribute__((ext_vector_type(8))) short bf16x8;   // 8 bf16 = 4 VGPRs
typedef __attribute__((ext_vector_type(16))) float f32x16;  // 32x32 mfma acc

#define NUM_PRIORS 11640
#define OUT_CH 25
#define BATCH 32

// ---------------- workspace layout (bytes) ----------------
// bf16 weights in MFMA-frag order: [tap][ck][ks][ntile][lane][8]
#define WT0 0u
#define WT1 1474560u
#define WT2 4423680u
#define WT3 5898240u
#define WT4 6635520u
#define WT5 7372800u
// fp32 conv output CONV[s][b][m=y*F+x][n=0..159]
#define CV0 8110080u
#define CV1 37683200u
#define CV2 45076480u
#define CV3 47124480u
#define CV4 47636480u
#define CV5 47820800u
#define WS_TOTAL 47841280u

// ====== fused weight prepass: OIHW fp32 -> bf16 frag order ===============
struct WArgs {
  const float* lw[6];
  const float* cw[6];
  unsigned short* wt[6];
};

template <int C>
__device__ __forceinline__
void wprep_body(int idx, const float* lw, const float* cw, unsigned short* wt)
{
  constexpr int CK = C / 64;
  if (idx >= 1440 * C) return;
  const int j    = idx & 7;
  const int lane = (idx >> 3) & 63;
  int rest = idx >> 9;
  const int nt  = rest % 5;  rest /= 5;
  const int ks  = rest & 3;  rest >>= 2;
  const int ck  = rest % CK;
  const int tap = rest / CK;
  const int n = nt * 32 + (lane & 31);
  const int c = ck * 64 + ks * 16 + (lane >> 5) * 8 + j;
  float v = 0.f;
  if (n < 24)       v = lw[((size_t)n        * C + c) * 9 + tap];
  else if (n < 150) v = cw[((size_t)(n - 24) * C + c) * 9 + tap];
  __hip_bfloat16 h = __float2bfloat16(v);
  wt[idx] = *(unsigned short*)&h;
}

// per-stage wprep block counts: 1440*C/256
#define WB0 2880
#define WB1 5760
#define WB2 2880
#define WB3 1440
#define WB4 1440
#define WB5 1440
#define WB_TOT (WB0 + WB1 + WB2 + WB3 + WB4 + WB5)

__global__ __launch_bounds__(256)
void wprep_all(WArgs a)
{
  int blk = blockIdx.x;
  const int t = threadIdx.x;
  if (blk < WB0) { wprep_body<512> (blk * 256 + t, a.lw[0], a.cw[0], a.wt[0]); return; } blk -= WB0;
  if (blk < WB1) { wprep_body<1024>(blk * 256 + t, a.lw[1], a.cw[1], a.wt[1]); return; } blk -= WB1;
  if (blk < WB2) { wprep_body<512> (blk * 256 + t, a.lw[2], a.cw[2], a.wt[2]); return; } blk -= WB2;
  if (blk < WB3) { wprep_body<256> (blk * 256 + t, a.lw[3], a.cw[3], a.wt[3]); return; } blk -= WB3;
  if (blk < WB4) { wprep_body<256> (blk * 256 + t, a.lw[4], a.cw[4], a.wt[4]); return; } blk -= WB4;
                   wprep_body<256> (blk * 256 + t, a.lw[5], a.cw[5], a.wt[5]);
}

// ====== fused implicit-GEMM conv (all 6 stages, one kernel) ==============
// per stage: block = 4 waves; m-tile 128 (4 x 32m), n = 160 (5 x 32); BK = 64 ch
template <int C, int F, int SPLIT>
__device__ __forceinline__
void conv_body(unsigned int* lP, int bid,
               const float* __restrict__ x, const unsigned short* __restrict__ wt,
               float* __restrict__ cv)
{
  constexpr int FF = F * F;
  constexpr int MB = (FF + 127) / 128;
  constexpr int CK = C / 64;
  constexpr int PCOLS = F + 2;
  constexpr int PR = ((127 / F + 4) < (F + 2)) ? (127 / F + 4) : (F + 2);
  constexpr int N4 = (PR * PCOLS + 3) / 4;
  constexpr int PP = N4 * 4;

  const int sp  = bid % SPLIT;
  const int mb  = (bid / SPLIT) % MB;
  const int b   = bid / (SPLIT * MB);
  const int ck0 = sp * CK / SPLIT;
  const int ck1 = (sp + 1) * CK / SPLIT;
  const int m0  = mb * 128;
  const int ylo = m0 / F;
  const int mtop = (m0 + 127) < (FF - 1) ? (m0 + 127) : (FF - 1);
  const int yhi = mtop / F;

  const int t    = threadIdx.x;
  const int wave = t >> 6, lane = t & 63;
  const int cm   = lane & 31, khalf = lane >> 5;
  int m_img = m0 + wave * 32 + cm;
  if (m_img > FF - 1) m_img = FF - 1;
  const int ay = m_img / F, ax = m_img - ay * F;
  const int pos0 = (ay - ylo) * PCOLS + ax;

  const float* x0 = x + (size_t)b * C * FF;

  f32x16 acc[5];
  #pragma unroll
  for (int nt = 0; nt < 5; ++nt)
    #pragma unroll
    for (int r = 0; r < 16; ++r) acc[nt][r] = 0.f;

  for (int ck = ck0; ck < ck1; ++ck) {
    __syncthreads();
    // ---- stage patch: 64 channels as 32 bf16-pairs ----
    #pragma unroll 1
    for (int e = t; e < 32 * N4; e += 256) {
      const int kk = e / N4;
      const int u4 = e - kk * N4;
      const float* s0 = x0 + (size_t)(ck * 64 + 2 * kk) * FF;
      const float* s1 = s0 + FF;
      unsigned int pk[4];
      #pragma unroll
      for (int q = 0; q < 4; ++q) {
        const int pos = u4 * 4 + q;
        const int pr  = pos / PCOLS;
        const int pc  = pos - pr * PCOLS;
        const int gy  = ylo - 1 + pr;
        const int gx  = pc - 1;
        float v0 = 0.f, v1 = 0.f;
        if (pos < PR * PCOLS && gy >= 0 && gy < F && gx >= 0 && gx < F) {
          v0 = s0[gy * F + gx];
          v1 = s1[gy * F + gx];
        }
        __hip_bfloat162 h = __float22bfloat162_rn(float2{v0, v1});
        pk[q] = *(unsigned int*)&h;
      }
      uint4 w4; w4.x = pk[0]; w4.y = pk[1]; w4.z = pk[2]; w4.w = pk[3];
      *(uint4*)&lP[kk * PP + u4 * 4] = w4;
    }
    __syncthreads();

    // ---- compute: 9 taps from same patch; B-frags direct from L2 ----
    const unsigned short* wck = wt + ck * 10240 + lane * 8;
    #pragma unroll
    for (int tap = 0; tap < 9; ++tap) {
      const int dy = tap / 3 - 1, dx = tap % 3 - 1;
      if (ylo + dy >= F || yhi + dy < 0) continue;   // block-uniform skip
      if (F == 1 && dx != 0) continue;
      const int pa = pos0 + (dy + 1) * PCOLS + (dx + 1);
      #pragma unroll
      for (int ks = 0; ks < 4; ++ks) {
        union { bf16x8 v; unsigned int u[4]; } af;
        #pragma unroll
        for (int i = 0; i < 4; ++i)
          af.u[i] = lP[(ks * 8 + khalf * 4 + i) * PP + pa];
        #pragma unroll
        for (int nt = 0; nt < 5; ++nt) {
          bf16x8 bfr = *(const bf16x8*)(wck + tap * (CK * 10240) + ks * 2560 + nt * 512);
          acc[nt] = __builtin_amdgcn_mfma_f32_32x32x16_bf16(af.v, bfr, acc[nt], 0, 0, 0);
        }
      }
    }
  }

  // ---- atomic-accumulate C (split-K) ----
  float* cbase = cv + (size_t)b * FF * 160;
  #pragma unroll
  for (int nt = 0; nt < 5; ++nt) {
    const int n = nt * 32 + cm;
    #pragma unroll
    for (int r = 0; r < 16; ++r) {
      const int mm  = wave * 32 + (r & 3) + 8 * (r >> 2) + 4 * khalf;
      const int m_g = m0 + mm;
      if (m_g < FF)
        atomicAdd(&cbase[(size_t)m_g * 160 + n], acc[nt][r]);
    }
  }
}

struct GArgs {
  const float* x[6];
  const unsigned short* wt[6];
  float* cv[6];
};

// block counts: 32 * MB * SPLIT  (LPT order: big stages first)
#define GB0 1536   // s0: MB=12, SPLIT=4
#define GB1 768    // s1: MB=3,  SPLIT=8
#define GB2 256    // s2: MB=1,  SPLIT=8
#define GB3 128    // s3: MB=1,  SPLIT=4
#define GB4 128    // s4: MB=1,  SPLIT=4
#define GB5 128    // s5: MB=1,  SPLIT=4
#define GB_TOT (GB0 + GB1 + GB2 + GB3 + GB4 + GB5)

__global__ __launch_bounds__(256, 3)
void gemm_all(GArgs a)
{
  __shared__ unsigned int lP[32 * 280];   // max PP (F=38) = 280
  int blk = blockIdx.x;
  if (blk < GB0) { conv_body<512,  38, 4>(lP, blk, a.x[0], a.wt[0], a.cv[0]); return; } blk -= GB0;
  if (blk < GB1) { conv_body<1024, 19, 8>(lP, blk, a.x[1], a.wt[1], a.cv[1]); return; } blk -= GB1;
  if (blk < GB2) { conv_body<512,  10, 8>(lP, blk, a.x[2], a.wt[2], a.cv[2]); return; } blk -= GB2;
  if (blk < GB3) { conv_body<256,   5, 4>(lP, blk, a.x[3], a.wt[3], a.cv[3]); return; } blk -= GB3;
  if (blk < GB4) { conv_body<256,   3, 4>(lP, blk, a.x[4], a.wt[4], a.cv[4]); return; } blk -= GB4;
                   conv_body<256,   1, 4>(lP, blk, a.x[5], a.wt[5], a.cv[5]);
}

// ================= decode: bias + softmax + prior decode ==================
struct DecArgs {
  const float* lb[6];
  const float* cb[6];
};

template <int F>
__device__ __forceinline__
void dec_one(int local, int b, const float* cvs, const float* lb, const float* cb,
             const float* p4, float* o)
{
  constexpr int FF = F * F;
  const int pos = local / 6;
  const int a   = local - pos * 6;
  const float* strip = cvs + ((size_t)b * FF + pos) * 160;

  float cls[21];
  float mx = -1e30f;
  #pragma unroll
  for (int k = 0; k < 21; ++k) {
    cls[k] = strip[24 + a * 21 + k] + cb[a * 21 + k];
    mx = fmaxf(mx, cls[k]);
  }
  float s = 0.f;
  #pragma unroll
  for (int k = 0; k < 21; ++k) { cls[k] = __expf(cls[k] - mx); s += cls[k]; }
  const float inv = 1.f / s;

  const float l0 = strip[a * 4 + 0] + lb[a * 4 + 0];
  const float l1 = strip[a * 4 + 1] + lb[a * 4 + 1];
  const float l2 = strip[a * 4 + 2] + lb[a * 4 + 2];
  const float l3 = strip[a * 4 + 3] + lb[a * 4 + 3];

  const float px = p4[0], py = p4[1], pw = p4[2], ph = p4[3];
  const float cx = px + l0 * 0.1f * pw;
  const float cy = py + l1 * 0.1f * ph;
  const float w  = pw * __expf(l2 * 0.2f);
  const float h  = ph * __expf(l3 * 0.2f);
  const float minx = cx - 0.5f * w;
  const float miny = cy - 0.5f * h;

  o[0] = minx; o[1] = miny; o[2] = minx + w; o[3] = miny + h;
  #pragma unroll
  for (int k = 0; k < 21; ++k) o[4 + k] = cls[k] * inv;
}

__global__ __launch_bounds__(256)
void decode_k(const char* __restrict__ wsb, DecArgs da,
              const float* __restrict__ priors, float* __restrict__ out)
{
  const int gid = blockIdx.x * 256 + threadIdx.x;
  if (gid >= BATCH * NUM_PRIORS) return;
  const int b  = gid / NUM_PRIORS;
  const int pr = gid - b * NUM_PRIORS;
  float* o = out + (size_t)gid * OUT_CH;
  const float* p4 = priors + (size_t)pr * 4;

  if (pr < 8664)       dec_one<38>(pr,         b, (const float*)(wsb + CV0), da.lb[0], da.cb[0], p4, o);
  else if (pr < 10830) dec_one<19>(pr - 8664,  b, (const float*)(wsb + CV1), da.lb[1], da.cb[1], p4, o);
  else if (pr < 11430) dec_one<10>(pr - 10830, b, (const float*)(wsb + CV2), da.lb[2], da.cb[2], p4, o);
  else if (pr < 11580) dec_one<5> (pr - 11430, b, (const float*)(wsb + CV3), da.lb[3], da.cb[3], p4, o);
  else if (pr < 11634) dec_one<3> (pr - 11580, b, (const float*)(wsb + CV4), da.lb[4], da.cb[4], p4, o);
  else                 dec_one<1> (pr - 11634, b, (const float*)(wsb + CV5), da.lb[5], da.cb[5], p4, o);
}

// ================= fallback (round-1 direct kernel, known-good) ===========
#define TH 4
#define TW 8
#define NPOS 32
#define NUM_OC 160
#define WS_STRIDE 161
#define OS 33
#define CC 8

union SmemFB {
  struct {
    float patch[CC * (TH + 2) * (TW + 2)];
    float w[9 * CC * WS_STRIDE];
  } st;
  float outbuf[NUM_OC * OS];
};

template <int C, int F>
__global__ __launch_bounds__(256)
void ssd_stage(const float* __restrict__ x,
               const float* __restrict__ loc_w, const float* __restrict__ loc_b,
               const float* __restrict__ conf_w, const float* __restrict__ conf_b,
               const float* __restrict__ priors,
               float* __restrict__ out, int stage_off)
{
  constexpr int nx = (F + TW - 1) / TW;
  constexpr int ny = (F + TH - 1) / TH;
  __shared__ SmemFB smem;

  const int bid = blockIdx.x;
  const int b   = bid / (nx * ny);
  const int rem = bid % (nx * ny);
  const int ty  = rem / nx;
  const int tx  = rem % nx;
  const int x0  = tx * TW;
  const int y0  = ty * TH;

  const int t = threadIdx.x;
  const int g = t & 31;
  const int p = t >> 5;

  float acc[5][TH] = {};

  #pragma unroll 1
  for (int c0 = 0; c0 < C; c0 += CC) {
    __syncthreads();
    for (int i = t; i < CC * (TH + 2) * (TW + 2); i += 256) {
      int c  = i / ((TH + 2) * (TW + 2));
      int r  = i - c * ((TH + 2) * (TW + 2));
      int yy = r / (TW + 2);
      int xx = r - yy * (TW + 2);
      int gy = y0 + yy - 1;
      int gx = x0 + xx - 1;
      float v = 0.f;
      if (gy >= 0 && gy < F && gx >= 0 && gx < F)
        v = x[(((size_t)b * C + (c0 + c)) * F + gy) * F + gx];
      smem.st.patch[i] = v;
    }
    for (int i = t; i < NUM_OC * (CC * 9); i += 256) {
      int oc  = i / (CC * 9);
      int j   = i - oc * (CC * 9);
      int c   = j / 9;
      int tap = j - c * 9;
      float v = 0.f;
      if (oc < 24)        v = loc_w [((size_t)oc        * C + (c0 + c)) * 9 + tap];
      else if (oc < 150)  v = conf_w[((size_t)(oc - 24) * C + (c0 + c)) * 9 + tap];
      smem.st.w[(tap * CC + c) * WS_STRIDE + oc] = v;
    }
    __syncthreads();

    for (int tap = 0; tap < 9; ++tap) {
      const int ky = tap / 3;
      const int kx = tap - ky * 3;
      const int xbase = ky * (TW + 2) + kx + p;
      const int wbase = tap * CC * WS_STRIDE + g;
      #pragma unroll
      for (int c = 0; c < CC; ++c) {
        float xv[TH];
        #pragma unroll
        for (int v = 0; v < TH; ++v)
          xv[v] = smem.st.patch[c * ((TH + 2) * (TW + 2)) + v * (TW + 2) + xbase];
        #pragma unroll
        for (int u = 0; u < 5; ++u) {
          float wv = smem.st.w[wbase + c * WS_STRIDE + u * 32];
          #pragma unroll
          for (int v = 0; v < TH; ++v)
            acc[u][v] += wv * xv[v];
        }
      }
    }
  }

  __syncthreads();
  #pragma unroll
  for (int u = 0; u < 5; ++u) {
    int oc = g + 32 * u;
    float bias = 0.f;
    if (oc < 24)       bias = loc_b[oc];
    else if (oc < 150) bias = conf_b[oc - 24];
    #pragma unroll
    for (int v = 0; v < TH; ++v)
      smem.outbuf[oc * OS + v * TW + p] = acc[u][v] + bias;
  }
  __syncthreads();

  if (t < NPOS * 6) {
    int pos = t / 6;
    int a   = t - pos * 6;
    int lx  = pos & 7;
    int ly  = pos >> 3;
    int gx  = x0 + lx;
    int gy  = y0 + ly;
    if (gx < F && gy < F) {
      float cls[21];
      float m = -1e30f;
      #pragma unroll
      for (int k = 0; k < 21; ++k) {
        cls[k] = smem.outbuf[(24 + a * 21 + k) * OS + pos];
        m = fmaxf(m, cls[k]);
      }
      float s = 0.f;
      #pragma unroll
      for (int k = 0; k < 21; ++k) { cls[k] = __expf(cls[k] - m); s += cls[k]; }
      float inv = 1.f / s;

      float l0 = smem.outbuf[(a * 4 + 0) * OS + pos];
      float l1 = smem.outbuf[(a * 4 + 1) * OS + pos];
      float l2 = smem.outbuf[(a * 4 + 2) * OS + pos];
      float l3 = smem.outbuf[(a * 4 + 3) * OS + pos];

      int prior = stage_off + (gy * F + gx) * 6 + a;
      const float* pr = priors + (size_t)prior * 4;
      float px = pr[0], py = pr[1], pw = pr[2], ph = pr[3];
      float cx = px + l0 * 0.1f * pw;
      float cy = py + l1 * 0.1f * ph;
      float w  = pw * __expf(l2 * 0.2f);
      float h  = ph * __expf(l3 * 0.2f);
      float minx = cx - 0.5f * w;
      float miny = cy - 0.5f * h;

      float* o = out + ((size_t)b * NUM_PRIORS + prior) * OUT_CH;
      o[0] = minx;
      o[1] = miny;
      o[2] = minx + w;
      o[3] = miny + h;
      #pragma unroll
      for (int k = 0; k < 21; ++k)
        o[4 + k] = cls[k] * inv;
    }
  }
}

template <int C, int F>
static void launch_stage_fb(void* const* d_in, int base, const float* priors, float* out,
                            int stage_off, hipStream_t stream) {
  constexpr int nx = (F + TW - 1) / TW;
  constexpr int ny = (F + TH - 1) / TH;
  int blocks = BATCH * nx * ny;
  ssd_stage<C, F><<<blocks, 256, 0, stream>>>(
      (const float*)d_in[base + 0], (const float*)d_in[base + 1], (const float*)d_in[base + 2],
      (const float*)d_in[base + 3], (const float*)d_in[base + 4], priors, out, stage_off);
}

// ================= launch =================================================
extern "C" void kernel_launch(void* const* d_in, const int* in_sizes, int n_in,
                              void* d_out, int out_size, void* d_ws, size_t ws_size,
                              hipStream_t stream) {
  (void)in_sizes; (void)n_in; (void)out_size;
  const float* priors = (const float*)d_in[30];
  float* out = (float*)d_out;

  if (ws_size < (size_t)WS_TOTAL) {   // deterministic fallback
    launch_stage_fb<512,  38>(d_in,  0, priors, out,     0, stream);
    launch_stage_fb<1024, 19>(d_in,  5, priors, out,  8664, stream);
    launch_stage_fb<512,  10>(d_in, 10, priors, out, 10830, stream);
    launch_stage_fb<256,   5>(d_in, 15, priors, out, 11430, stream);
    launch_stage_fb<256,   3>(d_in, 20, priors, out, 11580, stream);
    launch_stage_fb<256,   1>(d_in, 25, priors, out, 11634, stream);
    return;
  }

  char* wsb = (char*)d_ws;
  static const unsigned wtoff[6] = {WT0, WT1, WT2, WT3, WT4, WT5};
  static const unsigned cvoff[6] = {CV0, CV1, CV2, CV3, CV4, CV5};

  // fused weight prepass
  WArgs wa;
  for (int s = 0; s < 6; ++s) {
    wa.lw[s] = (const float*)d_in[5 * s + 1];
    wa.cw[s] = (const float*)d_in[5 * s + 3];
    wa.wt[s] = (unsigned short*)(wsb + wtoff[s]);
  }
  wprep_all<<<WB_TOT, 256, 0, stream>>>(wa);

  // zero all conv-accumulator regions (everything is split-K atomic now)
  hipMemsetAsync(wsb + CV0, 0, WS_TOTAL - CV0, stream);

  // fused implicit-GEMM convs
  GArgs ga;
  for (int s = 0; s < 6; ++s) {
    ga.x[s]  = (const float*)d_in[5 * s];
    ga.wt[s] = (const unsigned short*)(wsb + wtoff[s]);
    ga.cv[s] = (float*)(wsb + cvoff[s]);
  }
  gemm_all<<<GB_TOT, 256, 0, stream>>>(ga);

  // epilogue: bias + softmax + decode
  DecArgs da;
  for (int s = 0; s < 6; ++s) {
    da.lb[s] = (const float*)d_in[5 * s + 2];
    da.cb[s] = (const float*)d_in[5 * s + 4];
  }
  decode_k<<<(BATCH * NUM_PRIORS + 255) / 256, 256, 0, stream>>>((const char*)d_ws, da, priors, out);
}